// Round 8
// baseline (213.894 us; speedup 1.0000x reference)
//
#include <hip/hip_runtime.h>
#include <hip/hip_bf16.h>
#include <stdint.h>

typedef __attribute__((ext_vector_type(4))) float f32x4;
typedef __attribute__((ext_vector_type(16))) float f32x16;
typedef __attribute__((ext_vector_type(8))) short bf16x8;
typedef __attribute__((ext_vector_type(4))) int int4v;
typedef __attribute__((ext_vector_type(8))) unsigned short u16x8;
typedef unsigned int u32;

static __device__ __forceinline__ unsigned short f2bf(float f) {
    union { float f; unsigned u; } v; v.f = f;
    unsigned r = v.u + 0x7FFF + ((v.u >> 16) & 1);
    return (unsigned short)(r >> 16);
}

static __device__ __forceinline__ u32 cvtpk(float lo, float hi) {
    u32 r;
    asm("v_cvt_pk_bf16_f32 %0, %1, %2" : "=v"(r) : "v"(lo), "v"(hi));
    return r;
}

// v_permlane32_swap_b32 a, b : a_hi <-> b_lo (cross-lane half swap).
// SAFE ONLY when a and b provably hold distinct values (round-3 lesson).
static __device__ __forceinline__ void pl32swap_u(u32& a, u32& b) {
    asm("v_permlane32_swap_b32 %0, %1" : "+v"(a), "+v"(b));
}

static __device__ __forceinline__ void gload16(const void* g, void* lds) {
    __builtin_amdgcn_global_load_lds((const __attribute__((address_space(1))) void*)g,
                                     (__attribute__((address_space(3))) void*)lds,
                                     16, 0, 0);
}

// ---------------- kernel 0a: X fp32 -> bf16 ----------------
__global__ __launch_bounds__(256) void cvt_x_kernel(const float* __restrict__ x,
                                                    unsigned short* __restrict__ xb) {
    int i = (blockIdx.x * 256 + threadIdx.x) * 4;
    float4 v = *(const float4*)(x + i);
    ushort4 o = make_ushort4(f2bf(v.x), f2bf(v.y), f2bf(v.z), f2bf(v.w));
    *(ushort4*)(xb + i) = o;
}

// ---------------- kernel 0b: W [k][n] fp32 -> Wt [n][k] bf16 (x3) ----------------
__global__ __launch_bounds__(256) void cvt_w_kernel(const float* __restrict__ Wq,
                                                    const float* __restrict__ Wk,
                                                    const float* __restrict__ Wv,
                                                    unsigned short* __restrict__ Wt3) {
    const float* W = (blockIdx.z == 0) ? Wq : ((blockIdx.z == 1) ? Wk : Wv);
    unsigned short* out = Wt3 + (size_t)blockIdx.z * 1024 * 1024;
    __shared__ unsigned short t[64][68];
    int k0 = blockIdx.x * 64, n0 = blockIdx.y * 64;
    int tid = threadIdx.x;
#pragma unroll
    for (int i = 0; i < 4; i++) {
        int c = i * 256 + tid;
        int row = c >> 4, cb = c & 15;
        float4 v = *(const float4*)(W + (size_t)(k0 + row) * 1024 + n0 + cb * 4);
        ushort4 o = make_ushort4(f2bf(v.x), f2bf(v.y), f2bf(v.z), f2bf(v.w));
        *(ushort4*)(&t[row][cb * 4]) = o;
    }
    __syncthreads();
#pragma unroll
    for (int i = 0; i < 2; i++) {
        int c = i * 256 + tid;
        int n = c >> 3, kc = c & 7;
        u16x8 tmp;
#pragma unroll
        for (int j = 0; j < 8; j++) tmp[j] = t[kc * 8 + j][n];
        *(u16x8*)(&out[(size_t)(n0 + n) * 1024 + k0 + kc * 8]) = tmp;
    }
}

// ---------------- kernel 0c: mask reorder (per-lane register order, *8) ----------------
__global__ __launch_bounds__(256) void mask_reorder_kernel(const float* __restrict__ mask,
                                                           float* __restrict__ maskr) {
    int o = blockIdx.x * 256 + threadIdx.x;   // 0..8191
    int reg = o & 15, kvb = (o >> 4) & 1, hi2 = (o >> 5) & 1, kt = (o >> 6) & 31, bb = o >> 11;
    int kv = kt * 64 + kvb * 32 + (reg & 3) + 8 * (reg >> 2) + 4 * hi2;
    maskr[o] = 8.0f * mask[bb * 2048 + kv];
}

// ---------------- kernel 1: QKV GEMM, 128x128 tile, BK=32, 2-phase dbuf ----------------
// Pipeline per kt: barrier (drains buf[cur] loads issued last iter) -> issue
// gload_lds prefetch of kt+1 into buf[cur^1] -> compute buf[cur]. In-flight
// loads get the whole compute phase + next barrier-wait to land. LDS stays
// 32KB (2 x (8K A + 8K B)) so occupancy is unchanged vs single-buffer BK=64.
// XCD-bijective block remap (1536 blocks = 8 x 192): each XCD gets a
// contiguous run of m-tiles sharing one B-panel in its private L2.
__global__ __launch_bounds__(256) void qkv_gemm_kernel(
    const unsigned short* __restrict__ Xb,
    const unsigned short* __restrict__ Wt3,
    const float* __restrict__ bq, const float* __restrict__ bk, const float* __restrict__ bv,
    unsigned short* __restrict__ Qo, unsigned short* __restrict__ Ko,
    unsigned short* __restrict__ Vt)
{
    const int bid = blockIdx.x + 64 * blockIdx.y + 512 * blockIdx.z;
    const int nb = (bid & 7) * 192 + (bid >> 3);      // bijective (1536 % 8 == 0)
    const int z = nb / 512;
    const int rem = nb - z * 512;
    const int n0 = (rem >> 6) * 128;
    const int m0 = (rem & 63) * 128;

    const unsigned short* Wt = Wt3 + (size_t)z * 1048576;
    const float* bias = (z == 0) ? bq : ((z == 1) ? bk : bv);

    __shared__ __align__(16) unsigned short As[2][128 * 32];  // 8KB per buf
    __shared__ __align__(16) unsigned short Bs[2][128 * 32];

    const int tid = threadIdx.x, lane = tid & 63, wave = tid >> 6;
    const int wm = wave >> 1, wn = wave & 1;
    const int lr = lane & 15, lg = lane >> 4;

    // staging: chunk c = pass*256 + tid covers row c>>2, 16B slot c&3.
    // gload_lds dest: wave-uniform base (+ lane*16 by HW).
    const int c0row = tid >> 2, c0s = tid & 3;            // pass 0
    const int c1row = (256 + tid) >> 2, c1s = tid & 3;    // pass 1
    const unsigned short* aG0 = Xb + (size_t)(m0 + c0row) * 1024 + c0s * 8;
    const unsigned short* aG1 = Xb + (size_t)(m0 + c1row) * 1024 + c1s * 8;
    const unsigned short* bG0 = Wt + (size_t)(n0 + c0row) * 1024 + c0s * 8;
    const unsigned short* bG1 = Wt + (size_t)(n0 + c1row) * 1024 + c1s * 8;

    f32x4 acc[4][4] = {};

#define STAGE(bufi, kb)                                                         \
    do {                                                                        \
        gload16(aG0 + (kb), (char*)As + (bufi) * 8192 + wave * 1024);           \
        gload16(bG0 + (kb), (char*)Bs + (bufi) * 8192 + wave * 1024);           \
        gload16(aG1 + (kb), (char*)As + (bufi) * 8192 + 4096 + wave * 1024);    \
        gload16(bG1 + (kb), (char*)Bs + (bufi) * 8192 + 4096 + wave * 1024);    \
    } while (0)

    STAGE(0, 0);

#pragma unroll 2
    for (int kt = 0; kt < 32; kt++) {
        const int cur = kt & 1;
        __syncthreads();                 // buf[cur] ready; prior reads of buf[cur^1] done
        if (kt < 31) STAGE(cur ^ 1, (kt + 1) * 32);

        bf16x8 a[4], bb[4];
#pragma unroll
        for (int mi = 0; mi < 4; mi++)
            a[mi] = *(const bf16x8*)((char*)As + cur * 8192 + (wm * 64 + mi * 16 + lr) * 64 + lg * 16);
#pragma unroll
        for (int ni = 0; ni < 4; ni++)
            bb[ni] = *(const bf16x8*)((char*)Bs + cur * 8192 + (wn * 64 + ni * 16 + lr) * 64 + lg * 16);
#pragma unroll
        for (int mi = 0; mi < 4; mi++)
#pragma unroll
            for (int ni = 0; ni < 4; ni++)
                acc[mi][ni] = __builtin_amdgcn_mfma_f32_16x16x32_bf16(a[mi], bb[ni], acc[mi][ni], 0, 0, 0);
    }
#undef STAGE

    if (z < 2) {
        unsigned short* out = (z == 0) ? Qo : Ko;
#pragma unroll
        for (int ni = 0; ni < 4; ni++) {
            int n = n0 + wn * 64 + ni * 16 + lr;
            float bsv = bias[n];
#pragma unroll
            for (int mi = 0; mi < 4; mi++) {
                int mrow = m0 + wm * 64 + mi * 16 + lg * 4;
#pragma unroll
                for (int r = 0; r < 4; r++)
                    out[(size_t)(mrow + r) * 1024 + n] = f2bf(acc[mi][ni][r] + bsv);
            }
        }
    } else {
#pragma unroll
        for (int ni = 0; ni < 4; ni++) {
            int n = n0 + wn * 64 + ni * 16 + lr;
            float bsv = bias[n];
            int h = n >> 6, hd = n & 63;
#pragma unroll
            for (int mi = 0; mi < 4; mi++) {
                int mrow = m0 + wm * 64 + mi * 16 + lg * 4;
                int b = mrow >> 11, s = mrow & 2047;
                ushort4 pk = make_ushort4(f2bf(acc[mi][ni][0] + bsv),
                                          f2bf(acc[mi][ni][1] + bsv),
                                          f2bf(acc[mi][ni][2] + bsv),
                                          f2bf(acc[mi][ni][3] + bsv));
                *(ushort4*)(&Vt[((size_t)(b * 16 + h) * 64 + hd) * 2048 + s]) = pk;
            }
        }
    }
}

// ---------------- kernel 2: flash attention (unchanged from round 7) ----------------
// LDS: [Ks0:0][Ks1:8192][Vs0:16384][Vs1:24576][m0:32768][m1:33024]
__global__ __launch_bounds__(256) void attn_kernel(
    const unsigned short* __restrict__ Q,    // [B*S][1024] bf16
    const unsigned short* __restrict__ K,    // [B*S][1024] bf16
    const unsigned short* __restrict__ Vt,   // [B*H*64][2048] bf16 (V^T per head)
    const float* __restrict__ maskr,         // [B][32][64] reordered, *8
    float* __restrict__ out)                 // [B*S][1024] fp32
{
    __shared__ __align__(16) char smem[33280];
    const int tid = threadIdx.x, lane = tid & 63, w = tid >> 6;
    const int ln31 = lane & 31, hi = lane >> 5;
    const int bh = blockIdx.y, b = bh >> 4, h = bh & 15;
    const int q0 = blockIdx.x * 128 + w * 32;
    const int swz = (ln31 & 7) << 4;
    const float c1 = 0.18033688011112042f;   // 0.125 * log2(e)

    const unsigned short* Qrow = Q + (size_t)(b * 2048 + q0 + ln31) * 1024 + h * 64;
    bf16x8 aq[4];
#pragma unroll
    for (int ds = 0; ds < 4; ds++) aq[ds] = *(const bf16x8*)(Qrow + ds * 16 + hi * 8);

    const unsigned short* Kbp = K + (size_t)b * 2048 * 1024 + h * 64;
    const unsigned short* Vbp = Vt + (size_t)bh * 64 * 2048;

    const int r0 = tid >> 3, cb = tid & 7;
    const int woff = r0 * 128 + ((cb * 16) ^ ((r0 & 7) << 4));

    const unsigned short* kp = Kbp + (size_t)r0 * 1024 + cb * 8;   // +65536/tile
    const unsigned short* vp = Vbp + (size_t)r0 * 2048 + cb * 8;   // +64/tile
    const float* mp = maskr + (size_t)b * 2048 + tid * 4;          // +64/tile (tid<16)

    f32x16 oacc0 = {}, oacc1 = {};
    float mc = 8.0f * c1;   // fixed exp offset; raised only by rare slow path
    float lrun = 0.f;       // lane-local partial

    int4v kr0, kr1, vr0, vr1, mr = {};
    kr0 = *(const int4v*)kp; kr1 = *(const int4v*)(kp + 32 * 1024);
    vr0 = *(const int4v*)vp; vr1 = *(const int4v*)(vp + 32 * 2048);
    if (tid < 16) mr = *(const int4v*)mp;
    kp += 65536; vp += 64; mp += 64;
    *(int4v*)(smem + woff) = kr0;
    *(int4v*)(smem + 32 * 128 + woff) = kr1;
    *(int4v*)(smem + 16384 + woff) = vr0;
    *(int4v*)(smem + 16384 + 32 * 128 + woff) = vr1;
    if (tid < 16) *(int4v*)(smem + 32768 + tid * 16) = mr;
    kr0 = *(const int4v*)kp; kr1 = *(const int4v*)(kp + 32 * 1024);
    vr0 = *(const int4v*)vp; vr1 = *(const int4v*)(vp + 32 * 2048);
    if (tid < 16) mr = *(const int4v*)mp;
    kp += 65536; vp += 64; mp += 64;
    __syncthreads();

#pragma unroll 2
    for (int kt = 0; kt < 32; kt++) {
        const int cur = kt & 1;
        const char* KsL = smem + cur * 8192 + ln31 * 128;
        const char* VsL = KsL + 16384;
        const f32x4* mpl = (const f32x4*)(smem + 32768 + cur * 256 + hi * 128);

        f32x16 st0, st1;
        {
            f32x4 a0 = mpl[0], a1 = mpl[1], a2 = mpl[2], a3 = mpl[3];
            f32x4 a4 = mpl[4], a5 = mpl[5], a6 = mpl[6], a7 = mpl[7];
#pragma unroll
            for (int j = 0; j < 4; j++) {
                st0[j] = a0[j]; st0[4 + j] = a1[j]; st0[8 + j] = a2[j]; st0[12 + j] = a3[j];
                st1[j] = a4[j]; st1[4 + j] = a5[j]; st1[8 + j] = a6[j]; st1[12 + j] = a7[j];
            }
        }

        __builtin_amdgcn_s_setprio(1);
#pragma unroll
        for (int ds = 0; ds < 4; ds++) {
            const int co = (ds * 32 + hi * 16) ^ swz;
            bf16x8 ka0 = *(const bf16x8*)(KsL + co);
            bf16x8 ka1 = *(const bf16x8*)(KsL + 4096 + co);
            st0 = __builtin_amdgcn_mfma_f32_32x32x16_bf16(ka0, aq[ds], st0, 0, 0, 0);
            st1 = __builtin_amdgcn_mfma_f32_32x32x16_bf16(ka1, aq[ds], st1, 0, 0, 0);
        }
        __builtin_amdgcn_s_setprio(0);

        if (kt < 31) {
            char* base = smem + (cur ^ 1) * 8192;
            *(int4v*)(base + woff) = kr0;
            *(int4v*)(base + 32 * 128 + woff) = kr1;
            *(int4v*)(base + 16384 + woff) = vr0;
            *(int4v*)(base + 16384 + 32 * 128 + woff) = vr1;
            if (tid < 16) *(int4v*)(smem + 32768 + (cur ^ 1) * 256 + tid * 16) = mr;
            if (kt < 30) {
                kr0 = *(const int4v*)kp; kr1 = *(const int4v*)(kp + 32 * 1024);
                vr0 = *(const int4v*)vp; vr1 = *(const int4v*)(vp + 32 * 2048);
                if (tid < 16) mr = *(const int4v*)mp;
                kp += 65536; vp += 64; mp += 64;
            }
        }

        float s16[16];
#pragma unroll
        for (int j = 0; j < 16; j++) {
            float v0 = __builtin_amdgcn_exp2f(__builtin_fmaf(st0[j], c1, -mc));
            float v1 = __builtin_amdgcn_exp2f(__builtin_fmaf(st1[j], c1, -mc));
            st0[j] = v0; st1[j] = v1; s16[j] = v0 + v1;
        }
#pragma unroll
        for (int stp = 8; stp > 0; stp >>= 1)
#pragma unroll
            for (int j = 0; j < 8; j++) if (j < stp) s16[j] += s16[j + stp];

        if (__any(s16[0] > 256.0f)) {
            float me = st0[0];
#pragma unroll
            for (int j = 1; j < 16; j++) me = fmaxf(me, st0[j]);
#pragma unroll
            for (int j = 0; j < 16; j++) me = fmaxf(me, st1[j]);
            me = fmaxf(me, __shfl_xor(me, 32));
            me = fmaxf(me, 1.0f);
            const float al = 1.0f / me;
            mc += __log2f(me);
            lrun *= al; s16[0] *= al;
#pragma unroll
            for (int j = 0; j < 16; j++) {
                st0[j] *= al; st1[j] *= al;
                oacc0[j] *= al; oacc1[j] *= al;
            }
        }
        lrun += s16[0];

        __builtin_amdgcn_s_setprio(1);
#pragma unroll
        for (int s = 0; s < 4; s++) {
            const f32x16& pp = (s & 2) ? st1 : st0;
            const int rA = (s & 1) * 8, rB = rA + 4;
            u32 w0 = cvtpk(pp[rA + 0], pp[rA + 1]);
            u32 w1 = cvtpk(pp[rA + 2], pp[rA + 3]);
            u32 w2 = cvtpk(pp[rB + 0], pp[rB + 1]);
            u32 w3 = cvtpk(pp[rB + 2], pp[rB + 3]);
            pl32swap_u(w0, w2);
            pl32swap_u(w1, w3);
            union { u32 u[4]; bf16x8 v; } pb;
            pb.u[0] = w0; pb.u[1] = w1; pb.u[2] = w2; pb.u[3] = w3;
            const int co = (s * 32 + hi * 16) ^ swz;
            bf16x8 va0 = *(const bf16x8*)(VsL + co);
            bf16x8 va1 = *(const bf16x8*)(VsL + 4096 + co);
            oacc0 = __builtin_amdgcn_mfma_f32_32x32x16_bf16(va0, pb.v, oacc0, 0, 0, 0);
            oacc1 = __builtin_amdgcn_mfma_f32_32x32x16_bf16(va1, pb.v, oacc1, 0, 0, 0);
        }
        __builtin_amdgcn_s_setprio(0);

        __syncthreads();
    }

    float lt = lrun + __shfl_xor(lrun, 32);
    const float rl = 1.0f / lt;
    float* lw = (float*)(smem + w * 4096);   // per-wave 32hd x 32q f32
    const int qp = lane >> 1, hb = (lane & 1) * 16;
#pragma unroll
    for (int p = 0; p < 2; p++) {
        const f32x16& oa = p ? oacc1 : oacc0;
#pragma unroll
        for (int r = 0; r < 16; r++) {
            int hd = (r & 3) + 8 * (r >> 2) + 4 * hi;
            lw[hd * 32 + ln31] = oa[r] * rl;
        }
        float* od = out + (size_t)(b * 2048 + q0 + qp) * 1024 + h * 64 + p * 32 + hb;
#pragma unroll
        for (int c = 0; c < 4; c++) {
            f32x4 o4;
#pragma unroll
            for (int j = 0; j < 4; j++) o4[j] = lw[(hb + c * 4 + j) * 32 + qp];
            *(f32x4*)(od + c * 4) = o4;
        }
        __syncthreads();
    }
}

extern "C" void kernel_launch(void* const* d_in, const int* in_sizes, int n_in,
                              void* d_out, int out_size, void* d_ws, size_t ws_size,
                              hipStream_t stream) {
    const float* hs   = (const float*)d_in[0];
    const float* mask = (const float*)d_in[1];
    const float* Wq   = (const float*)d_in[2];
    const float* bq   = (const float*)d_in[3];
    const float* Wk   = (const float*)d_in[4];
    const float* bk   = (const float*)d_in[5];
    const float* Wv   = (const float*)d_in[6];
    const float* bv   = (const float*)d_in[7];
    float* out = (float*)d_out;

    char* ws = (char*)d_ws;
    unsigned short* Xb  = (unsigned short*)ws;                           // 16 MB
    unsigned short* Wt3 = (unsigned short*)(ws + 16777216);              // 6 MB
    unsigned short* Qb  = (unsigned short*)(ws + 16777216 + 6291456);    // 16 MB
    unsigned short* Kb  = Qb + 8388608;                                  // 16 MB
    unsigned short* Vt  = Kb + 8388608;                                  // 16 MB
    float* maskr = (float*)(ws + 16777216 + 6291456 + 3 * 16777216);     // 32 KB

    cvt_x_kernel<<<8192, 256, 0, stream>>>(hs, Xb);
    cvt_w_kernel<<<dim3(16, 16, 3), 256, 0, stream>>>(Wq, Wk, Wv, Wt3);
    mask_reorder_kernel<<<32, 256, 0, stream>>>(mask, maskr);
    qkv_gemm_kernel<<<dim3(64, 8, 3), 256, 0, stream>>>(Xb, Wt3, bq, bk, bv, Qb, Kb, Vt);
    attn_kernel<<<dim3(16, 64), 256, 0, stream>>>(Qb, Kb, Vt, maskr, out);
}

// Round 9
// 196.697 us; speedup vs baseline: 1.0874x; 1.0874x over previous
//
#include <hip/hip_runtime.h>
#include <hip/hip_bf16.h>
#include <stdint.h>

typedef __attribute__((ext_vector_type(4))) float f32x4;
typedef __attribute__((ext_vector_type(16))) float f32x16;
typedef __attribute__((ext_vector_type(8))) short bf16x8;
typedef __attribute__((ext_vector_type(4))) int int4v;
typedef __attribute__((ext_vector_type(2))) int int2v;
typedef __attribute__((ext_vector_type(8))) unsigned short u16x8;
typedef unsigned int u32;

static __device__ __forceinline__ unsigned short f2bf(float f) {
    union { float f; unsigned u; } v; v.f = f;
    unsigned r = v.u + 0x7FFF + ((v.u >> 16) & 1);
    return (unsigned short)(r >> 16);
}

static __device__ __forceinline__ u32 cvtpk(float lo, float hi) {
    u32 r;
    asm("v_cvt_pk_bf16_f32 %0, %1, %2" : "=v"(r) : "v"(lo), "v"(hi));
    return r;
}

// v_permlane32_swap_b32 a, b : a_hi <-> b_lo (cross-lane half swap).
// SAFE ONLY when a and b provably hold distinct values (round-3 lesson).
static __device__ __forceinline__ void pl32swap_u(u32& a, u32& b) {
    asm("v_permlane32_swap_b32 %0, %1" : "+v"(a), "+v"(b));
}

static __device__ __forceinline__ void gload16(const void* g, void* lds) {
    __builtin_amdgcn_global_load_lds((const __attribute__((address_space(1))) void*)g,
                                     (__attribute__((address_space(3))) void*)lds,
                                     16, 0, 0);
}

// ---------------- kernel 0a: X fp32 -> bf16 ----------------
__global__ __launch_bounds__(256) void cvt_x_kernel(const float* __restrict__ x,
                                                    unsigned short* __restrict__ xb) {
    int i = (blockIdx.x * 256 + threadIdx.x) * 4;
    float4 v = *(const float4*)(x + i);
    ushort4 o = make_ushort4(f2bf(v.x), f2bf(v.y), f2bf(v.z), f2bf(v.w));
    *(ushort4*)(xb + i) = o;
}

// ---------------- kernel 0b: W [k][n] fp32 -> Wt [n][k] bf16 (x3) ----------------
__global__ __launch_bounds__(256) void cvt_w_kernel(const float* __restrict__ Wq,
                                                    const float* __restrict__ Wk,
                                                    const float* __restrict__ Wv,
                                                    unsigned short* __restrict__ Wt3) {
    const float* W = (blockIdx.z == 0) ? Wq : ((blockIdx.z == 1) ? Wk : Wv);
    unsigned short* out = Wt3 + (size_t)blockIdx.z * 1024 * 1024;
    __shared__ unsigned short t[64][68];
    int k0 = blockIdx.x * 64, n0 = blockIdx.y * 64;
    int tid = threadIdx.x;
#pragma unroll
    for (int i = 0; i < 4; i++) {
        int c = i * 256 + tid;
        int row = c >> 4, cb = c & 15;
        float4 v = *(const float4*)(W + (size_t)(k0 + row) * 1024 + n0 + cb * 4);
        ushort4 o = make_ushort4(f2bf(v.x), f2bf(v.y), f2bf(v.z), f2bf(v.w));
        *(ushort4*)(&t[row][cb * 4]) = o;
    }
    __syncthreads();
#pragma unroll
    for (int i = 0; i < 2; i++) {
        int c = i * 256 + tid;
        int n = c >> 3, kc = c & 7;
        u16x8 tmp;
#pragma unroll
        for (int j = 0; j < 8; j++) tmp[j] = t[kc * 8 + j][n];
        *(u16x8*)(&out[(size_t)(n0 + n) * 1024 + k0 + kc * 8]) = tmp;
    }
}

// ---------------- kernel 0c: mask reorder (per-lane register order, *8) ----------------
__global__ __launch_bounds__(256) void mask_reorder_kernel(const float* __restrict__ mask,
                                                           float* __restrict__ maskr) {
    int o = blockIdx.x * 256 + threadIdx.x;   // 0..8191
    int reg = o & 15, kvb = (o >> 4) & 1, hi2 = (o >> 5) & 1, kt = (o >> 6) & 31, bb = o >> 11;
    int kv = kt * 64 + kvb * 32 + (reg & 3) + 8 * (reg >> 2) + 4 * hi2;
    maskr[o] = 8.0f * mask[bb * 2048 + kv];
}

// ---------------- kernel 1: QKV GEMM (bf16 MFMA, 128x128 tile, BK=64) ----------------
// r7 version (reverted r8 regression): gload_lds width-16, LINEAR LDS, natural grid.
__global__ __launch_bounds__(256) void qkv_gemm_kernel(
    const unsigned short* __restrict__ Xb,
    const unsigned short* __restrict__ Wt3,
    const float* __restrict__ bq, const float* __restrict__ bk, const float* __restrict__ bv,
    unsigned short* __restrict__ Qo, unsigned short* __restrict__ Ko,
    unsigned short* __restrict__ Vt)
{
    int z = blockIdx.z;
    const unsigned short* Wt = Wt3 + (size_t)z * 1048576;
    const float* bias = (z == 0) ? bq : ((z == 1) ? bk : bv);
    int m0 = blockIdx.x * 128, n0 = blockIdx.y * 128;

    __shared__ __align__(16) unsigned short As[128 * 64];  // linear [row][64*2B]
    __shared__ __align__(16) unsigned short Bs[128 * 64];

    int tid = threadIdx.x, lane = tid & 63, wave = tid >> 6;
    int wm = wave >> 1, wn = wave & 1;
    int lr = lane & 15, lg = lane >> 4;

    const int chunkrow = lane >> 3, colp = (lane & 7) * 8;
    const unsigned short* aBase = Xb + (size_t)(m0 + wave * 32 + chunkrow) * 1024 + colp;
    const unsigned short* bBase = Wt + (size_t)(n0 + wave * 32 + chunkrow) * 1024 + colp;
    char* lA = (char*)As + wave * 4096;
    char* lB = (char*)Bs + wave * 4096;

    f32x4 acc[4][4] = {};

    for (int kt = 0; kt < 16; kt++) {
        int kbase = kt * 64;
#pragma unroll
        for (int c = 0; c < 4; c++) {
            gload16(aBase + kbase + c * 8192, lA + c * 1024);
            gload16(bBase + kbase + c * 8192, lB + c * 1024);
        }
        __syncthreads();
#pragma unroll
        for (int kk = 0; kk < 2; kk++) {
            bf16x8 a[4], bb[4];
#pragma unroll
            for (int mi = 0; mi < 4; mi++)
                a[mi] = *(const bf16x8*)((char*)As + (wm * 64 + mi * 16 + lr) * 128 + kk * 64 + lg * 16);
#pragma unroll
            for (int ni = 0; ni < 4; ni++)
                bb[ni] = *(const bf16x8*)((char*)Bs + (wn * 64 + ni * 16 + lr) * 128 + kk * 64 + lg * 16);
#pragma unroll
            for (int mi = 0; mi < 4; mi++)
#pragma unroll
                for (int ni = 0; ni < 4; ni++)
                    acc[mi][ni] = __builtin_amdgcn_mfma_f32_16x16x32_bf16(a[mi], bb[ni], acc[mi][ni], 0, 0, 0);
        }
        __syncthreads();
    }

    if (z < 2) {
        unsigned short* out = (z == 0) ? Qo : Ko;
#pragma unroll
        for (int ni = 0; ni < 4; ni++) {
            int n = n0 + wn * 64 + ni * 16 + lr;
            float bsv = bias[n];
#pragma unroll
            for (int mi = 0; mi < 4; mi++) {
                int mrow = m0 + wm * 64 + mi * 16 + lg * 4;
#pragma unroll
                for (int r = 0; r < 4; r++)
                    out[(size_t)(mrow + r) * 1024 + n] = f2bf(acc[mi][ni][r] + bsv);
            }
        }
    } else {
#pragma unroll
        for (int ni = 0; ni < 4; ni++) {
            int n = n0 + wn * 64 + ni * 16 + lr;
            float bsv = bias[n];
            int h = n >> 6, hd = n & 63;
#pragma unroll
            for (int mi = 0; mi < 4; mi++) {
                int mrow = m0 + wm * 64 + mi * 16 + lg * 4;
                int b = mrow >> 11, s = mrow & 2047;
                ushort4 pk = make_ushort4(f2bf(acc[mi][ni][0] + bsv),
                                          f2bf(acc[mi][ni][1] + bsv),
                                          f2bf(acc[mi][ni][2] + bsv),
                                          f2bf(acc[mi][ni][3] + bsv));
                *(ushort4*)(&Vt[((size_t)(b * 16 + h) * 64 + hd) * 2048 + s]) = pk;
            }
        }
    }
}

// ---------------- kernel 2: flash attention, padded-stride LDS (conflict fix) ----------------
// K/V tiles stored with 136B row stride: bank = (34r + c/4)%32 -> 2r%32 -> 16
// groups x 2 lanes = 2-way (free, m136). 136B is 8B-aligned only, so frag
// access is ds_read_b64/ds_write_b64 pairs; no XOR swizzle needed.
// LDS: [Ks0:0][Ks1:8704][Vs0:17408][Vs1:26112][m0:34816][m1:35072] = 35328B
__global__ __launch_bounds__(256) void attn_kernel(
    const unsigned short* __restrict__ Q,    // [B*S][1024] bf16
    const unsigned short* __restrict__ K,    // [B*S][1024] bf16
    const unsigned short* __restrict__ Vt,   // [B*H*64][2048] bf16 (V^T per head)
    const float* __restrict__ maskr,         // [B][32][64] reordered, *8
    float* __restrict__ out)                 // [B*S][1024] fp32
{
    __shared__ __align__(16) char smem[35328];
    const int tid = threadIdx.x, lane = tid & 63, w = tid >> 6;
    const int ln31 = lane & 31, hi = lane >> 5;
    const int bh = blockIdx.y, b = bh >> 4, h = bh & 15;
    const int q0 = blockIdx.x * 128 + w * 32;
    const float c1 = 0.18033688011112042f;   // 0.125 * log2(e)
    const int VOFF = 17408, MOFF = 34816;

    const unsigned short* Qrow = Q + (size_t)(b * 2048 + q0 + ln31) * 1024 + h * 64;
    bf16x8 aq[4];
#pragma unroll
    for (int ds = 0; ds < 4; ds++) aq[ds] = *(const bf16x8*)(Qrow + ds * 16 + hi * 8);

    const unsigned short* Kbp = K + (size_t)b * 2048 * 1024 + h * 64;
    const unsigned short* Vbp = Vt + (size_t)bh * 64 * 2048;

    // staging coords: thread covers rows r0, r0+32 (16B chunk cb), written as 2x b64
    const int r0 = tid >> 3, cb = tid & 7;
    const int wA = r0 * 136 + cb * 16;
    const int wB = (r0 + 32) * 136 + cb * 16;

    const unsigned short* kp = Kbp + (size_t)r0 * 1024 + cb * 8;   // +65536/tile
    const unsigned short* vp = Vbp + (size_t)r0 * 2048 + cb * 8;   // +64/tile
    const float* mp = maskr + (size_t)b * 2048 + tid * 4;          // +64/tile (tid<16)

#define W64(dst, v4)                                            \
    do {                                                        \
        int2v _lo = {(v4)[0], (v4)[1]}, _hi = {(v4)[2], (v4)[3]}; \
        *(int2v*)(dst) = _lo;                                   \
        *(int2v*)((char*)(dst) + 8) = _hi;                      \
    } while (0)

    f32x16 oacc0 = {}, oacc1 = {};
    float mc = 8.0f * c1;   // fixed exp offset; raised only by rare slow path
    float lrun = 0.f;       // lane-local partial

    int4v kr0, kr1, vr0, vr1, mr = {};
    kr0 = *(const int4v*)kp; kr1 = *(const int4v*)(kp + 32 * 1024);
    vr0 = *(const int4v*)vp; vr1 = *(const int4v*)(vp + 32 * 2048);
    if (tid < 16) mr = *(const int4v*)mp;
    kp += 65536; vp += 64; mp += 64;
    W64(smem + wA, kr0);
    W64(smem + wB, kr1);
    W64(smem + VOFF + wA, vr0);
    W64(smem + VOFF + wB, vr1);
    if (tid < 16) *(int4v*)(smem + MOFF + tid * 16) = mr;
    kr0 = *(const int4v*)kp; kr1 = *(const int4v*)(kp + 32 * 1024);
    vr0 = *(const int4v*)vp; vr1 = *(const int4v*)(vp + 32 * 2048);
    if (tid < 16) mr = *(const int4v*)mp;
    kp += 65536; vp += 64; mp += 64;
    __syncthreads();

#pragma unroll 2
    for (int kt = 0; kt < 32; kt++) {
        const int cur = kt & 1;
        const char* KsL = smem + cur * 8704 + ln31 * 136;
        const char* VsL = smem + VOFF + cur * 8704 + ln31 * 136;
        const f32x4* mpl = (const f32x4*)(smem + MOFF + cur * 256 + hi * 128);

        f32x16 st0, st1;
        {
            f32x4 a0 = mpl[0], a1 = mpl[1], a2 = mpl[2], a3 = mpl[3];
            f32x4 a4 = mpl[4], a5 = mpl[5], a6 = mpl[6], a7 = mpl[7];
#pragma unroll
            for (int j = 0; j < 4; j++) {
                st0[j] = a0[j]; st0[4 + j] = a1[j]; st0[8 + j] = a2[j]; st0[12 + j] = a3[j];
                st1[j] = a4[j]; st1[4 + j] = a5[j]; st1[8 + j] = a6[j]; st1[12 + j] = a7[j];
            }
        }

        __builtin_amdgcn_s_setprio(1);
#pragma unroll
        for (int ds = 0; ds < 4; ds++) {
            const int co = ds * 32 + hi * 16;
            union { int2v h[2]; bf16x8 v; } ka0, ka1;
            ka0.h[0] = *(const int2v*)(KsL + co);
            ka0.h[1] = *(const int2v*)(KsL + co + 8);
            ka1.h[0] = *(const int2v*)(KsL + 4352 + co);
            ka1.h[1] = *(const int2v*)(KsL + 4352 + co + 8);
            st0 = __builtin_amdgcn_mfma_f32_32x32x16_bf16(ka0.v, aq[ds], st0, 0, 0, 0);
            st1 = __builtin_amdgcn_mfma_f32_32x32x16_bf16(ka1.v, aq[ds], st1, 0, 0, 0);
        }
        __builtin_amdgcn_s_setprio(0);

        // ---- EARLY: stage tile kt+1 (regs) -> buf[cur^1]; prefetch tile kt+2 ----
        if (kt < 31) {
            char* kb = smem + (cur ^ 1) * 8704;
            char* vb = smem + VOFF + (cur ^ 1) * 8704;
            W64(kb + wA, kr0);
            W64(kb + wB, kr1);
            W64(vb + wA, vr0);
            W64(vb + wB, vr1);
            if (tid < 16) *(int4v*)(smem + MOFF + (cur ^ 1) * 256 + tid * 16) = mr;
            if (kt < 30) {
                kr0 = *(const int4v*)kp; kr1 = *(const int4v*)(kp + 32 * 1024);
                vr0 = *(const int4v*)vp; vr1 = *(const int4v*)(vp + 32 * 2048);
                if (tid < 16) mr = *(const int4v*)mp;
                kp += 65536; vp += 64; mp += 64;
            }
        }

        float s16[16];
#pragma unroll
        for (int j = 0; j < 16; j++) {
            float v0 = __builtin_amdgcn_exp2f(__builtin_fmaf(st0[j], c1, -mc));
            float v1 = __builtin_amdgcn_exp2f(__builtin_fmaf(st1[j], c1, -mc));
            st0[j] = v0; st1[j] = v1; s16[j] = v0 + v1;
        }
#pragma unroll
        for (int stp = 8; stp > 0; stp >>= 1)
#pragma unroll
            for (int j = 0; j < 8; j++) if (j < stp) s16[j] += s16[j + stp];

        if (__any(s16[0] > 256.0f)) {
            float me = st0[0];
#pragma unroll
            for (int j = 1; j < 16; j++) me = fmaxf(me, st0[j]);
#pragma unroll
            for (int j = 0; j < 16; j++) me = fmaxf(me, st1[j]);
            me = fmaxf(me, __shfl_xor(me, 32));
            me = fmaxf(me, 1.0f);
            const float al = 1.0f / me;
            mc += __log2f(me);
            lrun *= al; s16[0] *= al;
#pragma unroll
            for (int j = 0; j < 16; j++) {
                st0[j] *= al; st1[j] *= al;
                oacc0[j] *= al; oacc1[j] *= al;
            }
        }
        lrun += s16[0];

        __builtin_amdgcn_s_setprio(1);
#pragma unroll
        for (int s = 0; s < 4; s++) {
            const f32x16& pp = (s & 2) ? st1 : st0;
            const int rA = (s & 1) * 8, rB = rA + 4;
            u32 w0 = cvtpk(pp[rA + 0], pp[rA + 1]);
            u32 w1 = cvtpk(pp[rA + 2], pp[rA + 3]);
            u32 w2 = cvtpk(pp[rB + 0], pp[rB + 1]);
            u32 w3 = cvtpk(pp[rB + 2], pp[rB + 3]);
            pl32swap_u(w0, w2);
            pl32swap_u(w1, w3);
            union { u32 u[4]; bf16x8 v; } pb;
            pb.u[0] = w0; pb.u[1] = w1; pb.u[2] = w2; pb.u[3] = w3;
            const int co = s * 32 + hi * 16;
            union { int2v h[2]; bf16x8 v; } va0, va1;
            va0.h[0] = *(const int2v*)(VsL + co);
            va0.h[1] = *(const int2v*)(VsL + co + 8);
            va1.h[0] = *(const int2v*)(VsL + 4352 + co);
            va1.h[1] = *(const int2v*)(VsL + 4352 + co + 8);
            oacc0 = __builtin_amdgcn_mfma_f32_32x32x16_bf16(va0.v, pb.v, oacc0, 0, 0, 0);
            oacc1 = __builtin_amdgcn_mfma_f32_32x32x16_bf16(va1.v, pb.v, oacc1, 0, 0, 0);
        }
        __builtin_amdgcn_s_setprio(0);

        __syncthreads();
    }
#undef W64

    float lt = lrun + __shfl_xor(lrun, 32);
    const float rl = 1.0f / lt;
    float* lw = (float*)(smem + w * 4096);   // per-wave 32hd x 32q f32
    const int qp = lane >> 1, hb = (lane & 1) * 16;
#pragma unroll
    for (int p = 0; p < 2; p++) {
        const f32x16& oa = p ? oacc1 : oacc0;
#pragma unroll
        for (int r = 0; r < 16; r++) {
            int hd = (r & 3) + 8 * (r >> 2) + 4 * hi;
            lw[hd * 32 + ln31] = oa[r] * rl;
        }
        float* od = out + (size_t)(b * 2048 + q0 + qp) * 1024 + h * 64 + p * 32 + hb;
#pragma unroll
        for (int c = 0; c < 4; c++) {
            f32x4 o4;
#pragma unroll
            for (int j = 0; j < 4; j++) o4[j] = lw[(hb + c * 4 + j) * 32 + qp];
            *(f32x4*)(od + c * 4) = o4;
        }
        __syncthreads();
    }
}

extern "C" void kernel_launch(void* const* d_in, const int* in_sizes, int n_in,
                              void* d_out, int out_size, void* d_ws, size_t ws_size,
                              hipStream_t stream) {
    const float* hs   = (const float*)d_in[0];
    const float* mask = (const float*)d_in[1];
    const float* Wq   = (const float*)d_in[2];
    const float* bq   = (const float*)d_in[3];
    const float* Wk   = (const float*)d_in[4];
    const float* bk   = (const float*)d_in[5];
    const float* Wv   = (const float*)d_in[6];
    const float* bv   = (const float*)d_in[7];
    float* out = (float*)d_out;

    char* ws = (char*)d_ws;
    unsigned short* Xb  = (unsigned short*)ws;                           // 16 MB
    unsigned short* Wt3 = (unsigned short*)(ws + 16777216);              // 6 MB
    unsigned short* Qb  = (unsigned short*)(ws + 16777216 + 6291456);    // 16 MB
    unsigned short* Kb  = Qb + 8388608;                                  // 16 MB
    unsigned short* Vt  = Kb + 8388608;                                  // 16 MB
    float* maskr = (float*)(ws + 16777216 + 6291456 + 3 * 16777216);     // 32 KB

    cvt_x_kernel<<<8192, 256, 0, stream>>>(hs, Xb);
    cvt_w_kernel<<<dim3(16, 16, 3), 256, 0, stream>>>(Wq, Wk, Wv, Wt3);
    mask_reorder_kernel<<<32, 256, 0, stream>>>(mask, maskr);
    qkv_gemm_kernel<<<dim3(64, 8, 3), 256, 0, stream>>>(Xb, Wt3, bq, bk, bv, Qb, Kb, Vt);
    attn_kernel<<<dim3(16, 64), 256, 0, stream>>>(Qb, Kb, Vt, maskr, out);
}